// Round 1
// baseline (94.171 us; speedup 1.0000x reference)
//
#include <hip/hip_runtime.h>
#include <hip/hip_bf16.h>

#define NE 800000   // edges
#define NN 50000    // nodes
#define TPW 4       // edge-tiles (of 16 edges) per wave

typedef __attribute__((ext_vector_type(8))) short    s16x8;
typedef __attribute__((ext_vector_type(8))) __bf16   bf16x8;
typedef __attribute__((ext_vector_type(4))) float    f32x4;
typedef __attribute__((ext_vector_type(2))) float    f32x2;

__device__ __forceinline__ unsigned short f2bf_bits(float f) {
    __bf16 b = (__bf16)f;
    return __builtin_bit_cast(unsigned short, b);
}

__device__ __forceinline__ s16x8 cvt8(f32x4 a, f32x4 b) {
    bf16x8 r;
    r[0] = (__bf16)a[0]; r[1] = (__bf16)a[1]; r[2] = (__bf16)a[2]; r[3] = (__bf16)a[3];
    r[4] = (__bf16)b[0]; r[5] = (__bf16)b[1]; r[6] = (__bf16)b[2]; r[7] = (__bf16)b[3];
    return __builtin_bit_cast(s16x8, r);
}

// Pre-transpose weights to bf16, j-major (B-operand friendly), K zero-padded.
// ws layout (unsigned short elems):
//   w1t [64][160]  (K 130 -> 160, rows j = output feature)
//   w2t [32][64]
//   w3t [16][32]
__global__ void prep_weights(const float* __restrict__ W1, const float* __restrict__ W2,
                             const float* __restrict__ W3, unsigned short* __restrict__ ws) {
    unsigned short* w1t = ws;              // 10240 elems
    unsigned short* w2t = ws + 64 * 160;   // 2048 elems
    unsigned short* w3t = w2t + 32 * 64;   // 512 elems
    int t = blockIdx.x * blockDim.x + threadIdx.x;
    int stride = gridDim.x * blockDim.x;
    for (int i = t; i < 64 * 160; i += stride) {
        int j = i / 160, k = i % 160;
        w1t[i] = f2bf_bits(k < 130 ? W1[k * 64 + j] : 0.0f);
    }
    for (int i = t; i < 32 * 64; i += stride) {
        int j = i / 64, k = i % 64;
        w2t[i] = f2bf_bits(W2[k * 32 + j]);
    }
    for (int i = t; i < 16 * 32; i += stride) {
        int j = i / 32, k = i % 32;
        w3t[i] = f2bf_bits(W3[k * 16 + j]);
    }
}

// One wave = 16 edges per tile, TPW tiles. No inter-wave communication, no barriers.
// MFMA 16x16x32 bf16 layouts (m89-verified):
//   A: lane holds A[row=lane&15][k=(lane>>4)*8 + b], b=0..7
//   B: lane holds B[k=(lane>>4)*8 + b][col=lane&15]
//   C/D: lane holds D[row=(lane>>4)*4 + r][col=lane&15], r=0..3
__global__ __launch_bounds__(256) void edge_mlp(
    const float* __restrict__ nf, const int* __restrict__ ei,
    const float* __restrict__ sp, const float* __restrict__ b1,
    const float* __restrict__ b2, const float* __restrict__ b3,
    const unsigned short* __restrict__ wsw, float* __restrict__ out) {

    const unsigned short* w1t = wsw;
    const unsigned short* w2t = wsw + 64 * 160;
    const unsigned short* w3t = w2t + 32 * 64;

    // per-wave activation transpose buffers (strides padded to dodge bank conflicts)
    __shared__ float h1s[4][16][68];
    __shared__ float h2s[4][16][36];

    const int tid  = threadIdx.x;
    const int wid  = tid >> 6;
    const int lane = tid & 63;
    const int lr   = lane & 15;   // row (A/edges) or col (B,C/D)
    const int lg   = lane >> 4;   // 4-lane group -> k/row chunk

    // Weight fragments, register-resident across the whole tile loop.
    s16x8 w1f[5][4];   // [K-step][col-tile]
    s16x8 w2f[2][2];
    s16x8 w3f;
    #pragma unroll
    for (int s = 0; s < 5; ++s)
        #pragma unroll
        for (int c = 0; c < 4; ++c)
            w1f[s][c] = *reinterpret_cast<const s16x8*>(w1t + (c * 16 + lr) * 160 + s * 32 + lg * 8);
    #pragma unroll
    for (int s = 0; s < 2; ++s)
        #pragma unroll
        for (int c = 0; c < 2; ++c)
            w2f[s][c] = *reinterpret_cast<const s16x8*>(w2t + (c * 16 + lr) * 64 + s * 32 + lg * 8);
    w3f = *reinterpret_cast<const s16x8*>(w3t + lr * 32 + lg * 8);

    float bias1[4], bias2[2], bias3;
    #pragma unroll
    for (int c = 0; c < 4; ++c) bias1[c] = b1[c * 16 + lr];
    #pragma unroll
    for (int c = 0; c < 2; ++c) bias2[c] = b2[c * 16 + lr];
    bias3 = b3[lr];

    const int tile0 = (blockIdx.x * 4 + wid) * TPW;

    for (int tt = 0; tt < TPW; ++tt) {
        const int tile = tile0 + tt;
        if (tile >= NE / 16) break;
        const int ebase = tile * 16;
        const int e  = ebase + lr;          // this lane's gather edge
        const int si = ei[e];
        const int di = ei[NE + e];

        // ---- layer 1: [16 x 160] @ [160 x 64] ----
        f32x4 acc1[4];
        #pragma unroll
        for (int c = 0; c < 4; ++c) acc1[c] = (f32x4){0.f, 0.f, 0.f, 0.f};

        #pragma unroll
        for (int s = 0; s < 5; ++s) {
            s16x8 af;
            if (s < 4) {
                const float* p = nf + (long)(s < 2 ? si : di) * 64 + (s & 1) * 32 + lg * 8;
                f32x4 a = *reinterpret_cast<const f32x4*>(p);
                f32x4 b = *reinterpret_cast<const f32x4*>(p + 4);
                af = cvt8(a, b);
            } else {
                bf16x8 z;
                #pragma unroll
                for (int j = 0; j < 8; ++j) z[j] = (__bf16)0.0f;
                if (lg == 0) {
                    f32x2 s2 = *reinterpret_cast<const f32x2*>(sp + 2 * e);
                    z[0] = (__bf16)s2[0];
                    z[1] = (__bf16)s2[1];
                }
                af = __builtin_bit_cast(s16x8, z);
            }
            #pragma unroll
            for (int c = 0; c < 4; ++c)
                acc1[c] = __builtin_amdgcn_mfma_f32_16x16x32_bf16(af, w1f[s][c], acc1[c], 0, 0, 0);
        }

        // bias + relu, transpose C-layout -> A-layout via per-wave LDS
        #pragma unroll
        for (int c = 0; c < 4; ++c)
            #pragma unroll
            for (int r = 0; r < 4; ++r)
                h1s[wid][lg * 4 + r][c * 16 + lr] = fmaxf(acc1[c][r] + bias1[c], 0.0f);

        // ---- layer 2: [16 x 64] @ [64 x 32] ----
        f32x4 acc2[2];
        #pragma unroll
        for (int c = 0; c < 2; ++c) acc2[c] = (f32x4){0.f, 0.f, 0.f, 0.f};
        #pragma unroll
        for (int s = 0; s < 2; ++s) {
            f32x4 a = *reinterpret_cast<const f32x4*>(&h1s[wid][lr][s * 32 + lg * 8]);
            f32x4 b = *reinterpret_cast<const f32x4*>(&h1s[wid][lr][s * 32 + lg * 8 + 4]);
            s16x8 af = cvt8(a, b);
            #pragma unroll
            for (int c = 0; c < 2; ++c)
                acc2[c] = __builtin_amdgcn_mfma_f32_16x16x32_bf16(af, w2f[s][c], acc2[c], 0, 0, 0);
        }
        #pragma unroll
        for (int c = 0; c < 2; ++c)
            #pragma unroll
            for (int r = 0; r < 4; ++r)
                h2s[wid][lg * 4 + r][c * 16 + lr] = fmaxf(acc2[c][r] + bias2[c], 0.0f);

        // ---- layer 3: [16 x 32] @ [32 x 16] ----
        f32x4 a3 = *reinterpret_cast<const f32x4*>(&h2s[wid][lr][lg * 8]);
        f32x4 b3v = *reinterpret_cast<const f32x4*>(&h2s[wid][lr][lg * 8 + 4]);
        s16x8 af3 = cvt8(a3, b3v);
        f32x4 acc3 = (f32x4){0.f, 0.f, 0.f, 0.f};
        acc3 = __builtin_amdgcn_mfma_f32_16x16x32_bf16(af3, w3f, acc3, 0, 0, 0);

        #pragma unroll
        for (int r = 0; r < 4; ++r)
            out[(long)(ebase + lg * 4 + r) * 16 + lr] = acc3[r] + bias3;
    }
}

extern "C" void kernel_launch(void* const* d_in, const int* in_sizes, int n_in,
                              void* d_out, int out_size, void* d_ws, size_t ws_size,
                              hipStream_t stream) {
    const float* nf = (const float*)d_in[0];
    const int*   ei = (const int*)d_in[1];
    const float* sp = (const float*)d_in[2];
    const float* W1 = (const float*)d_in[3];
    const float* b1 = (const float*)d_in[4];
    const float* W2 = (const float*)d_in[5];
    const float* b2 = (const float*)d_in[6];
    const float* W3 = (const float*)d_in[7];
    const float* b3 = (const float*)d_in[8];
    float* out = (float*)d_out;
    unsigned short* wsw = (unsigned short*)d_ws;

    hipLaunchKernelGGL(prep_weights, dim3(32), dim3(256), 0, stream, W1, W2, W3, wsw);

    const int tiles  = NE / 16;                 // 50000
    const int waves  = (tiles + TPW - 1) / TPW; // 12500
    const int blocks = (waves + 3) / 4;         // 3125
    hipLaunchKernelGGL(edge_mlp, dim3(blocks), dim3(256), 0, stream,
                       nf, ei, sp, b1, b2, b3, wsw, out);
}

// Round 2
// 72.288 us; speedup vs baseline: 1.3027x; 1.3027x over previous
//
#include <hip/hip_runtime.h>
#include <hip/hip_bf16.h>

#define NE 800000   // edges
#define NN 50000    // nodes
#define TPW 4       // edge-tiles (of 16 edges) per wave

typedef __attribute__((ext_vector_type(8))) short    s16x8;
typedef __attribute__((ext_vector_type(8))) __bf16   bf16x8;
typedef __attribute__((ext_vector_type(4))) float    f32x4;
typedef __attribute__((ext_vector_type(2))) float    f32x2;

// ws layout (unsigned short elems):
//   [0)        w1t [64][160]   10240
//   [10240)    w2t [32][64]     2048
//   [12288)    w3t [16][32]      512
//   [16384)    nfb [NN][64]  bf16 node table (optional, needs ws_size >= 6432768 B)
#define NFB_OFF 16384
#define WS_NEED ((size_t)(NFB_OFF + (size_t)NN * 64) * 2)

__device__ __forceinline__ unsigned short f2bf_bits(float f) {
    __bf16 b = (__bf16)f;
    return __builtin_bit_cast(unsigned short, b);
}

__device__ __forceinline__ s16x8 cvt8(f32x4 a, f32x4 b) {
    bf16x8 r;
    r[0] = (__bf16)a[0]; r[1] = (__bf16)a[1]; r[2] = (__bf16)a[2]; r[3] = (__bf16)a[3];
    r[4] = (__bf16)b[0]; r[5] = (__bf16)b[1]; r[6] = (__bf16)b[2]; r[7] = (__bf16)b[3];
    return __builtin_bit_cast(s16x8, r);
}

__global__ void prep(const float* __restrict__ W1, const float* __restrict__ W2,
                     const float* __restrict__ W3, const float* __restrict__ nf,
                     unsigned short* __restrict__ ws, int do_nf) {
    unsigned short* w1t = ws;
    unsigned short* w2t = ws + 10240;
    unsigned short* w3t = ws + 12288;
    int t = blockIdx.x * blockDim.x + threadIdx.x;
    int stride = gridDim.x * blockDim.x;
    for (int i = t; i < 64 * 160; i += stride) {
        int j = i / 160, k = i % 160;
        w1t[i] = f2bf_bits(k < 130 ? W1[k * 64 + j] : 0.0f);
    }
    for (int i = t; i < 32 * 64; i += stride) {
        int j = i / 64, k = i % 64;
        w2t[i] = f2bf_bits(W2[k * 32 + j]);
    }
    for (int i = t; i < 16 * 32; i += stride) {
        int j = i / 32, k = i % 32;
        w3t[i] = f2bf_bits(W3[k * 16 + j]);
    }
    if (do_nf) {
        unsigned short* nfb = ws + NFB_OFF;
        // 8 floats -> one s16x8 store per iteration
        for (int i = t; i < NN * 8; i += stride) {
            f32x4 a = *reinterpret_cast<const f32x4*>(nf + (long)i * 8);
            f32x4 b = *reinterpret_cast<const f32x4*>(nf + (long)i * 8 + 4);
            *reinterpret_cast<s16x8*>(nfb + (long)i * 8) = cvt8(a, b);
        }
    }
}

// MFMA 16x16x32 bf16 layouts (m89-verified):
//   A: lane holds A[row=lane&15][k=(lane>>4)*8 + b], b=0..7
//   B: lane holds B[k=(lane>>4)*8 + b][col=lane&15]
//   C/D: lane holds D[row=(lane>>4)*4 + r][col=lane&15], r=0..3
template <bool BF16NF>
__device__ __forceinline__ void gather4(const unsigned short* nfb, const float* nf,
                                        int si, int di, int lg, s16x8 g[4]) {
    if (BF16NF) {
        #pragma unroll
        for (int s = 0; s < 4; ++s) {
            const int row = (s < 2) ? si : di;
            g[s] = *reinterpret_cast<const s16x8*>(nfb + (long)row * 64 + (s & 1) * 32 + lg * 8);
        }
    } else {
        #pragma unroll
        for (int s = 0; s < 4; ++s) {
            const float* p = nf + (long)((s < 2) ? si : di) * 64 + (s & 1) * 32 + lg * 8;
            f32x4 a = *reinterpret_cast<const f32x4*>(p);
            f32x4 b = *reinterpret_cast<const f32x4*>(p + 4);
            g[s] = cvt8(a, b);
        }
    }
}

template <bool BF16NF>
__global__ __launch_bounds__(256) void edge_mlp(
    const float* __restrict__ nf, const int* __restrict__ ei,
    const float* __restrict__ sp, const float* __restrict__ b1,
    const float* __restrict__ b2, const float* __restrict__ b3,
    const unsigned short* __restrict__ wsw, float* __restrict__ out) {

    const unsigned short* w1t = wsw;
    const unsigned short* w2t = wsw + 10240;
    const unsigned short* w3t = wsw + 12288;
    const unsigned short* nfb = wsw + NFB_OFF;

    __shared__ float h1s[4][16][68];
    __shared__ float h2s[4][16][36];

    const int tid  = threadIdx.x;
    const int wid  = tid >> 6;
    const int lane = tid & 63;
    const int lr   = lane & 15;
    const int lg   = lane >> 4;

    // Register-resident weight fragments.
    s16x8 w1f[5][4];
    s16x8 w2f[2][2];
    s16x8 w3f;
    #pragma unroll
    for (int s = 0; s < 5; ++s)
        #pragma unroll
        for (int c = 0; c < 4; ++c)
            w1f[s][c] = *reinterpret_cast<const s16x8*>(w1t + (c * 16 + lr) * 160 + s * 32 + lg * 8);
    #pragma unroll
    for (int s = 0; s < 2; ++s)
        #pragma unroll
        for (int c = 0; c < 2; ++c)
            w2f[s][c] = *reinterpret_cast<const s16x8*>(w2t + (c * 16 + lr) * 64 + s * 32 + lg * 8);
    w3f = *reinterpret_cast<const s16x8*>(w3t + lr * 32 + lg * 8);

    float bias1[4], bias2[2], bias3;
    #pragma unroll
    for (int c = 0; c < 4; ++c) bias1[c] = b1[c * 16 + lr];
    #pragma unroll
    for (int c = 0; c < 2; ++c) bias2[c] = b2[c * 16 + lr];
    bias3 = b3[lr];

    const int tile0 = (blockIdx.x * 4 + wid) * TPW;

    // Prologue: all edge indices + spatial for this wave's TPW tiles.
    int si[TPW], di[TPW];
    f32x2 spv[TPW];
    #pragma unroll
    for (int t = 0; t < TPW; ++t) {
        const int e = (tile0 + t) * 16 + lr;
        si[t] = ei[e];
        di[t] = ei[NE + e];
        spv[t] = *reinterpret_cast<const f32x2*>(sp + 2 * e);
    }

    // Software pipeline: gather tile t+1 while computing tile t.
    s16x8 cur[4], nxt[4];
    gather4<BF16NF>(nfb, nf, si[0], di[0], lg, cur);

    #pragma unroll
    for (int tt = 0; tt < TPW; ++tt) {
        if (tt + 1 < TPW)
            gather4<BF16NF>(nfb, nf, si[tt + 1], di[tt + 1], lg, nxt);

        const int ebase = (tile0 + tt) * 16;

        // ---- layer 1: [16 x 160] @ [160 x 64] ----
        f32x4 acc1[4];
        #pragma unroll
        for (int c = 0; c < 4; ++c) acc1[c] = (f32x4){0.f, 0.f, 0.f, 0.f};

        #pragma unroll
        for (int s = 0; s < 4; ++s)
            #pragma unroll
            for (int c = 0; c < 4; ++c)
                acc1[c] = __builtin_amdgcn_mfma_f32_16x16x32_bf16(cur[s], w1f[s][c], acc1[c], 0, 0, 0);

        {   // spatial K-step (k=128..159, only k=128,129 nonzero, lg==0 lanes)
            bf16x8 z;
            #pragma unroll
            for (int j = 0; j < 8; ++j) z[j] = (__bf16)0.0f;
            if (lg == 0) { z[0] = (__bf16)spv[tt][0]; z[1] = (__bf16)spv[tt][1]; }
            s16x8 af = __builtin_bit_cast(s16x8, z);
            #pragma unroll
            for (int c = 0; c < 4; ++c)
                acc1[c] = __builtin_amdgcn_mfma_f32_16x16x32_bf16(af, w1f[4][c], acc1[c], 0, 0, 0);
        }

        // bias + relu, transpose C-layout -> A-layout via per-wave LDS
        #pragma unroll
        for (int c = 0; c < 4; ++c)
            #pragma unroll
            for (int r = 0; r < 4; ++r)
                h1s[wid][lg * 4 + r][c * 16 + lr] = fmaxf(acc1[c][r] + bias1[c], 0.0f);

        // ---- layer 2: [16 x 64] @ [64 x 32] ----
        f32x4 acc2[2];
        #pragma unroll
        for (int c = 0; c < 2; ++c) acc2[c] = (f32x4){0.f, 0.f, 0.f, 0.f};
        #pragma unroll
        for (int s = 0; s < 2; ++s) {
            f32x4 a = *reinterpret_cast<const f32x4*>(&h1s[wid][lr][s * 32 + lg * 8]);
            f32x4 b = *reinterpret_cast<const f32x4*>(&h1s[wid][lr][s * 32 + lg * 8 + 4]);
            s16x8 af = cvt8(a, b);
            #pragma unroll
            for (int c = 0; c < 2; ++c)
                acc2[c] = __builtin_amdgcn_mfma_f32_16x16x32_bf16(af, w2f[s][c], acc2[c], 0, 0, 0);
        }
        #pragma unroll
        for (int c = 0; c < 2; ++c)
            #pragma unroll
            for (int r = 0; r < 4; ++r)
                h2s[wid][lg * 4 + r][c * 16 + lr] = fmaxf(acc2[c][r] + bias2[c], 0.0f);

        // ---- layer 3: [16 x 32] @ [32 x 16] ----
        f32x4 a3 = *reinterpret_cast<const f32x4*>(&h2s[wid][lr][lg * 8]);
        f32x4 b3v = *reinterpret_cast<const f32x4*>(&h2s[wid][lr][lg * 8 + 4]);
        s16x8 af3 = cvt8(a3, b3v);
        f32x4 acc3 = (f32x4){0.f, 0.f, 0.f, 0.f};
        acc3 = __builtin_amdgcn_mfma_f32_16x16x32_bf16(af3, w3f, acc3, 0, 0, 0);

        #pragma unroll
        for (int r = 0; r < 4; ++r)
            out[(long)(ebase + lg * 4 + r) * 16 + lr] = acc3[r] + bias3;

        #pragma unroll
        for (int s = 0; s < 4; ++s) cur[s] = nxt[s];
    }
}

extern "C" void kernel_launch(void* const* d_in, const int* in_sizes, int n_in,
                              void* d_out, int out_size, void* d_ws, size_t ws_size,
                              hipStream_t stream) {
    const float* nf = (const float*)d_in[0];
    const int*   ei = (const int*)d_in[1];
    const float* sp = (const float*)d_in[2];
    const float* W1 = (const float*)d_in[3];
    const float* b1 = (const float*)d_in[4];
    const float* W2 = (const float*)d_in[5];
    const float* b2 = (const float*)d_in[6];
    const float* W3 = (const float*)d_in[7];
    const float* b3 = (const float*)d_in[8];
    float* out = (float*)d_out;
    unsigned short* wsw = (unsigned short*)d_ws;

    const bool bf16nf = (ws_size >= WS_NEED);

    hipLaunchKernelGGL(prep, dim3(1024), dim3(256), 0, stream,
                       W1, W2, W3, nf, wsw, bf16nf ? 1 : 0);

    const int tiles  = NE / 16;                 // 50000
    const int waves  = (tiles + TPW - 1) / TPW; // 12500
    const int blocks = (waves + 3) / 4;         // 3125

    if (bf16nf)
        hipLaunchKernelGGL(edge_mlp<true>, dim3(blocks), dim3(256), 0, stream,
                           nf, ei, sp, b1, b2, b3, wsw, out);
    else
        hipLaunchKernelGGL(edge_mlp<false>, dim3(blocks), dim3(256), 0, stream,
                           nf, ei, sp, b1, b2, b3, wsw, out);
}